// Round 23
// baseline (165.171 us; speedup 1.0000x reference)
//
#include <hip/hip_runtime.h>

typedef unsigned long long u64;
typedef unsigned short u16;
typedef __bf16 bf16_t;
typedef bf16_t bf16x8 __attribute__((ext_vector_type(8)));
typedef _Float16 f16_t;
typedef f16_t f16x8 __attribute__((ext_vector_type(8)));
typedef f16_t f16x2 __attribute__((ext_vector_type(2)));
typedef __fp16 h16n_t;
typedef h16n_t h16n2 __attribute__((ext_vector_type(2)));
typedef float f32x4 __attribute__((ext_vector_type(4)));
typedef float f32x2 __attribute__((ext_vector_type(2)));

#define NN 4096
#define NH 3
#define NPAIR 131072
#define LOG2E 1.4426950408889634f

union U8 { uint4 u; bf16x8 b; };
union UH { uint4 u; f16x8 h; };
union UH2 { f16x2 h; unsigned int u; };
union UHN2 { h16n2 h; unsigned int u; };

__device__ __forceinline__ u16 f2us(float f) {
  unsigned int x = __float_as_uint(f);
  x = x + 0x7fffu + ((x >> 16) & 1u);
  return (u16)(x >> 16);
}
__device__ __forceinline__ float us2f(u16 u) {
  return __uint_as_float(((unsigned int)u) << 16);
}
__device__ __forceinline__ unsigned int pk2(float a, float b) {
  return (unsigned int)f2us(a) | ((unsigned int)f2us(b) << 16);
}
__device__ __forceinline__ unsigned int pkh2(float a, float b) {
#if __has_builtin(__builtin_amdgcn_cvt_pkrtz)
  UHN2 cv;
  cv.h = __builtin_amdgcn_cvt_pkrtz(a, b);
  return cv.u;
#else
  UH2 cv;
  cv.h[0] = (f16_t)a;
  cv.h[1] = (f16_t)b;
  return cv.u;
#endif
}
__device__ __forceinline__ u16 f2h16(float a) {
  UH2 cv;
  cv.h[0] = (f16_t)a;
  cv.h[1] = (f16_t)0.f;
  return (u16)(cv.u & 0xffffu);
}
__device__ __forceinline__ f16x2 h2max(f16x2 a, f16x2 b) {
  f16x2 r;
  r[0] = a[0] > b[0] ? a[0] : b[0];
  r[1] = a[1] > b[1] ? a[1] : b[1];
  return r;
}
__device__ __forceinline__ float exp2fast(float x) {
#if __has_builtin(__builtin_amdgcn_exp2f)
  return __builtin_amdgcn_exp2f(x);
#else
  return __expf(x * 0.6931471805599453f);
#endif
}
// A&S 7.1.26 erf approx, |err| <= 1.5e-7 (abs)
__device__ __forceinline__ float erf_fast(float x) {
  float ax = fabsf(x);
  float t = 1.f / fmaf(0.3275911f, ax, 1.f);
  float poly =
      t * (0.254829592f +
           t * (-0.284496736f +
                t * (1.421413741f +
                     t * (-1.453152027f + t * 1.061405429f))));
  float e = exp2fast(-ax * ax * LOG2E);
  float r = 1.f - poly * e;
  return x < 0.f ? -r : r;
}
__device__ __forceinline__ float geluf(float x) {
  return 0.5f * x * (1.f + erf_fast(x * 0.70710678118654752f));
}
__device__ __forceinline__ void gl_lds16(const u16* g, u16* s) {
  __builtin_amdgcn_global_load_lds(
      (const __attribute__((address_space(1))) unsigned int*)g,
      (__attribute__((address_space(3))) unsigned int*)s, 16, 0, 0);
}

// ---- adj int32 [N][N] -> bitmask u64 [N][N/64] (4096 blocks, streaming) ----
__global__ __launch_bounds__(256) void k_bitmask(const int* __restrict__ adj,
                                                 u64* __restrict__ bm) {
  int i = blockIdx.x;
  int lane = threadIdx.x & 63;
  int wv = threadIdx.x >> 6;
  const int* row = adj + (size_t)i * NN;
  for (int wq = wv; wq < NN / 64; wq += 4) {
    u64 b = __ballot(row[wq * 64 + lane] > 0);
    if (lane == 0) bm[(size_t)i * (NN / 64) + wq] = b;
  }
}

// ---- fragment-major mask: bmF[ib(64)][jc(128)][lane(64)] u32 = 4 m-bytes ----
__global__ __launch_bounds__(256) void k_maskf(const u64* __restrict__ bm,
                                               unsigned int* __restrict__ bmF) {
  int idx = blockIdx.x * 256 + threadIdx.x;  // 524288 total
  int l = idx & 63, jc = (idx >> 6) & 127, ib = idx >> 13;
  int li = l & 15, lg = l >> 4;
  const unsigned char* b8 = (const unsigned char*)bm;
  unsigned int v = 0;
#pragma unroll
  for (int m = 0; m < 4; ++m)
    v |= (unsigned int)b8[(size_t)(ib * 64 + m * 16 + li) * 512 + jc * 4 + lg]
         << (8 * m);
  bmF[idx] = v;
}

// ---- bf16/f16 tables ----
__global__ __launch_bounds__(256) void k_prep(
    const float* __restrict__ emb, const float* __restrict__ W1,
    const float* __restrict__ W2, const float* __restrict__ linW,
    u16* __restrict__ emb16, u16* __restrict__ WT1, u16* __restrict__ WT2,
    u16* __restrict__ linWTh) {
  int idx = blockIdx.x * 256 + threadIdx.x;
  if (idx < 1048576) { emb16[idx] = f2us(emb[idx]); return; }
  idx -= 1048576;
  if (idx < 98304) {
    int h = idx / 32768, r = idx & 32767, f = r >> 8, k = r & 255;
    WT1[idx] = f2us(W1[h * 32768 + k * 128 + f]);
    return;
  }
  idx -= 98304;
  if (idx < 147456) {
    int h = idx / 49152, r = idx % 49152, f = r / 384, k = r % 384;
    WT2[idx] = f2us(W2[h * 49152 + k * 128 + f]);
    return;
  }
  idx -= 147456;
  if (idx < 49152) {
    int f = idx / 384, k = idx % 384;
    linWTh[idx] = f2h16(linW[k * 128 + f]);  // f16 for k_pairs
  }
}

// ---- Wh = x @ W via MFMA, v2: x-row loaded upfront, 3-deep register B
//      prefetch, fully unrolled (all static indices); 1 wave / 16 rows ----
template <int K>
__global__ __launch_bounds__(64, 2) void k_wh(const u16* __restrict__ xb,
                                              const u16* __restrict__ WT,
                                              const float* __restrict__ av,
                                              u16* __restrict__ WhTF,
                                              float* __restrict__ E1,
                                              float* __restrict__ F1,
                                              u16* __restrict__ E2h,
                                              u16* __restrict__ F2h) {
  constexpr int NS = K / 32;
  int h = blockIdx.y, l = threadIdx.x, li = l & 15, lg = l >> 4;
  int iw = blockIdx.x * 16;
  const u16* Wb = WT + (size_t)h * 128 * K;
  const u16* xr = xb + (size_t)(iw + li) * K;

  f32x4 acc[8];
#pragma unroll
  for (int nt = 0; nt < 8; ++nt) acc[nt] = (f32x4){0.f, 0.f, 0.f, 0.f};

  uint4 xa[NS];
#pragma unroll
  for (int s = 0; s < NS; ++s)
    xa[s] = *(const uint4*)(xr + s * 32 + lg * 8);

  uint4 bbuf[3][8];
#define LDB(S)                                                               \
  do {                                                                       \
    _Pragma("unroll") for (int nt = 0; nt < 8; ++nt)                         \
        bbuf[(S) % 3][nt] = *(const uint4*)(Wb + (size_t)(nt * 16 + li) * K +\
                                            (S) * 32 + lg * 8);              \
  } while (0)

#pragma unroll
  for (int pf = 0; pf < 3; ++pf) {
    if (pf < NS) LDB(pf);
  }
#pragma unroll
  for (int s = 0; s < NS; ++s) {
    U8 af;
    af.u = xa[s];
#pragma unroll
    for (int nt = 0; nt < 8; ++nt) {
      U8 bb;
      bb.u = bbuf[s % 3][nt];
      acc[nt] = __builtin_amdgcn_mfma_f32_16x16x32_bf16(af.b, bb.b, acc[nt], 0, 0, 0);
    }
    if (s + 3 < NS) LDB(s + 3);
  }
#undef LDB

  float p1[4] = {0.f, 0.f, 0.f, 0.f}, p2[4] = {0.f, 0.f, 0.f, 0.f};
#pragma unroll
  for (int nt = 0; nt < 8; ++nt) {
    float a1 = av[h * 256 + nt * 16 + li];
    float a2 = av[h * 256 + 128 + nt * 16 + li];
#pragma unroll
    for (int r = 0; r < 4; ++r) {
      p1[r] = fmaf(acc[nt][r], a1, p1[r]);
      p2[r] = fmaf(acc[nt][r], a2, p2[r]);
    }
  }
#pragma unroll
  for (int r = 0; r < 4; ++r) {
#pragma unroll
    for (int o = 1; o < 16; o <<= 1) {
      p1[r] += __shfl_xor(p1[r], o);
      p2[r] += __shfl_xor(p2[r], o);
    }
  }
  if (li == 0) {
#pragma unroll
    for (int r = 0; r < 4; ++r) {
      int idx = h * NN + iw + lg * 4 + r;
      float s1L = p1[r] * LOG2E, s2L = p2[r] * LOG2E;
      E1[idx] = exp2fast(s1L);
      F1[idx] = exp2fast(0.2f * s1L);
      E2h[idx] = f2h16(exp2fast(s2L));
      F2h[idx] = f2h16(exp2fast(0.2f * s2L));
    }
  }
  // fragment-major f16 write
  u16* Wo = WhTF + (size_t)h * 524288;
  int jc = iw >> 5, jin = (iw & 31) + lg * 4;
#pragma unroll
  for (int nt = 0; nt < 8; ++nt) {
    uint2 pw;
    pw.x = pkh2(acc[nt][0], acc[nt][1]);
    pw.y = pkh2(acc[nt][2], acc[nt][3]);
    *(uint2*)(Wo + (size_t)nt * 65536 + (size_t)jc * 512 + li * 32 + jin) = pw;
  }
}

// ---- attention accumulate v8 (f16): 4-wave/256-thr blocks, wave = M=32 x
//      N=128 x K=512 (kq=8); grid 32x8x3 = 768 = 3 blocks/CU; counted
//      vmcnt(2) pipeline; packed-f16 p-compute; f16 MFMA; T5 setprio ----
#define WAITC(N)                                                  \
  do {                                                            \
    asm volatile("s_waitcnt vmcnt(" #N ")" ::: "memory");         \
    __builtin_amdgcn_sched_barrier(0);                            \
    __builtin_amdgcn_s_barrier();                                 \
    __builtin_amdgcn_sched_barrier(0);                            \
  } while (0)
#define ROT3(X) X = (X == 2) ? 0 : X + 1

__global__ __launch_bounds__(256, 3) void k_acc(
    const unsigned int* __restrict__ bmF, const u16* __restrict__ WhTF,
    const float* __restrict__ E1, const float* __restrict__ F1,
    const u16* __restrict__ E2h, const u16* __restrict__ F2h,
    u16* __restrict__ Pp, float* __restrict__ dnP) {
  __shared__ __align__(16) u16 Bl[3][4096];  // 3 x 8KB
  int h = blockIdx.y, t = threadIdx.x, w = t >> 6, l = t & 63;
  int li = l & 15, lg = l >> 4;
  int rt = blockIdx.x >> 3, kq = blockIdx.x & 7;  // 32 rt x 8 kq
  int iw0 = rt * 128 + w * 32;
  int k0 = kq * 512;
  int perm = (l & 15) * 4 + (l >> 4);
  const u16* gsrcA = WhTF + (size_t)h * 524288 + (size_t)w * 65536 +
                     (size_t)(k0 >> 5) * 512 + perm * 8;
  const u16* gsrcB = gsrcA + (size_t)4 * 65536;
  const u16* E2p = E2h + h * NN;
  const u16* F2p = F2h + h * NN;
  f16x2 e1h[2], f1h[2];
#pragma unroll
  for (int mg = 0; mg < 2; ++mg) {
    f16_t e1 = (f16_t)E1[h * NN + iw0 + mg * 16 + li];
    f16_t f1 = (f16_t)F1[h * NN + iw0 + mg * 16 + li];
    e1h[mg][0] = e1; e1h[mg][1] = e1;
    f1h[mg][0] = f1; f1h[mg][1] = f1;
  }
  int mq0 = (iw0 >> 4) & 3;
  const unsigned int* mrow =
      bmF + ((size_t)(iw0 >> 6) * 128 + (k0 >> 5)) * 64 + l;

  f32x4 acc[2][8];
  f32x4 accD[2];
#pragma unroll
  for (int mg = 0; mg < 2; ++mg) {
    accD[mg] = (f32x4){0.f, 0.f, 0.f, 0.f};
#pragma unroll
    for (int nt = 0; nt < 8; ++nt) acc[mg][nt] = (f32x4){0.f, 0.f, 0.f, 0.f};
  }
  UH ones;
  ones.u = make_uint4(0x3C003C00u, 0x3C003C00u, 0x3C003C00u, 0x3C003C00u);

#define STG2(B, S)                                        \
  do {                                                    \
    gl_lds16(gsrcA + (size_t)(S) * 512, &Bl[B][w * 512]); \
    gl_lds16(gsrcB + (size_t)(S) * 512, &Bl[B][(w + 4) * 512]); \
  } while (0)
#define LDSC(SUF, S)                                      \
  do {                                                    \
    int j0_ = k0 + (S) * 32;                              \
    mw##SUF = mrow[(S) * 64];                             \
    Eu##SUF = *(const uint4*)(E2p + j0_ + lg * 8);        \
    Fu##SUF = *(const uint4*)(F2p + j0_ + lg * 8);        \
  } while (0)
#define BODY(SUF)                                                            \
  do {                                                                       \
    unsigned int ew_[4] = {Eu##SUF.x, Eu##SUF.y, Eu##SUF.z, Eu##SUF.w};      \
    unsigned int fw_[4] = {Fu##SUF.x, Fu##SUF.y, Fu##SUF.z, Fu##SUF.w};      \
    UH A_[2];                                                                \
    _Pragma("unroll") for (int mg = 0; mg < 2; ++mg) {                       \
      unsigned int mb_ = (mw##SUF >> (8 * (mq0 + mg))) & 0xffu;              \
      unsigned int aw_[4];                                                   \
      _Pragma("unroll") for (int q = 0; q < 4; ++q) {                        \
        UH2 eh_, fh_, ph_;                                                   \
        eh_.u = ew_[q];                                                      \
        fh_.u = fw_[q];                                                      \
        ph_.h = h2max(e1h[mg] * eh_.h, f1h[mg] * fh_.h);                     \
        unsigned int sel_ = (((mb_ >> (2 * q)) & 1u) ? 0xFFFFu : 0u) |       \
                            (((mb_ >> (2 * q + 1)) & 1u) ? 0xFFFF0000u : 0u);\
        aw_[q] = ph_.u & sel_;                                               \
      }                                                                      \
      A_[mg].u = make_uint4(aw_[0], aw_[1], aw_[2], aw_[3]);                 \
    }                                                                        \
    const u16* bl_ = &Bl[bcur][0] + l * 8;                                   \
    __builtin_amdgcn_s_setprio(1);                                           \
    _Pragma("unroll") for (int nt = 0; nt < 8; ++nt) {                       \
      UH B_;                                                                 \
      B_.u = *(const uint4*)(bl_ + nt * 512);                                \
      acc[0][nt] = __builtin_amdgcn_mfma_f32_16x16x32_f16(A_[0].h, B_.h,     \
                                                  acc[0][nt], 0, 0, 0);      \
      acc[1][nt] = __builtin_amdgcn_mfma_f32_16x16x32_f16(A_[1].h, B_.h,     \
                                                  acc[1][nt], 0, 0, 0);      \
    }                                                                        \
    accD[0] = __builtin_amdgcn_mfma_f32_16x16x32_f16(A_[0].h, ones.h,        \
                                                     accD[0], 0, 0, 0);      \
    accD[1] = __builtin_amdgcn_mfma_f32_16x16x32_f16(A_[1].h, ones.h,        \
                                                     accD[1], 0, 0, 0);      \
    __builtin_amdgcn_s_setprio(0);                                           \
    ROT3(bcur);                                                              \
  } while (0)

  unsigned int mwA, mwB;
  uint4 EuA, FuA, EuB, FuB;
  int bcur = 0, bstg = 2;
  LDSC(A, 0);
  STG2(0, 0);
  STG2(1, 1);
#pragma unroll 1
  for (int s = 0; s < 16; s += 2) {
    WAITC(2);
    LDSC(B, s + 1);
    if (s + 2 < 16) { STG2(bstg, s + 2); ROT3(bstg); }
    BODY(A);
    if (s + 1 == 15) { WAITC(0); } else { WAITC(2); }
    if (s + 2 < 16) LDSC(A, s + 2);
    if (s + 3 < 16) { STG2(bstg, s + 3); ROT3(bstg); }
    BODY(B);
  }
#undef STG2
#undef LDSC
#undef BODY

#pragma unroll
  for (int mg = 0; mg < 2; ++mg) {
    size_t rbase = (size_t)(kq * 3 + h) * NN + iw0 + mg * 16;
#pragma unroll
    for (int nt = 0; nt < 8; ++nt)
#pragma unroll
      for (int r = 0; r < 4; ++r)
        Pp[(rbase + lg * 4 + r) * 128 + nt * 16 + li] = f2us(acc[mg][nt][r]);
    if (li == 0) {
#pragma unroll
      for (int r = 0; r < 4; ++r)
        dnP[rbase + lg * 4 + r] = accD[mg][r];
    }
  }
}

// ---- finalize: sum 8 bf16 K-chunk partials, /dn, ELU, mix; mode1 -> f16
//      pair-table att16 in step-packed layout [st(12)][lg(4)][8 f16] ----
__global__ __launch_bounds__(256) void k_fin(
    const u16* __restrict__ Pp, const float* __restrict__ dnP,
    const float* __restrict__ at1f_in, const float* __restrict__ amix,
    const float* __restrict__ bmix, float* __restrict__ at1f_out,
    u16* __restrict__ at1b_out, u16* __restrict__ att16_out, int mode) {
  int gid = blockIdx.x * 256 + threadIdx.x;
  int c4 = gid & 31, row = (gid >> 5) & 4095, h = gid >> 17;
  size_t off = ((size_t)h * NN + row) * 128 + c4 * 4;
  const size_t ks = (size_t)3 * NN * 128;
  float s[4] = {0.f, 0.f, 0.f, 0.f};
  float dsum = 0.f;
#pragma unroll
  for (int q = 0; q < 8; ++q) {
    uint2 v = *(const uint2*)(Pp + q * ks + off);
    s[0] += us2f((u16)(v.x & 0xffffu));
    s[1] += us2f((u16)(v.x >> 16));
    s[2] += us2f((u16)(v.y & 0xffffu));
    s[3] += us2f((u16)(v.y >> 16));
    dsum += dnP[(size_t)(q * 3 + h) * NN + row];
  }
  float inv = 1.f / fmaxf(dsum, 1e-30f);
#pragma unroll
  for (int q = 0; q < 4; ++q) {
    s[q] *= inv;
    s[q] = s[q] > 0.f ? s[q] : (exp2fast(s[q] * LOG2E) - 1.f);
  }
  size_t oi = (size_t)row * 384 + h * 128 + c4 * 4;
  if (mode == 0) {
    *(float4*)(at1f_out + oi) = make_float4(s[0], s[1], s[2], s[3]);
    uint2 pb;
    pb.x = pk2(s[0], s[1]);
    pb.y = pk2(s[2], s[3]);
    *(uint2*)(at1b_out + oi) = pb;
  } else {
    float Am = amix[0], Bm = bmix[0];
    float wa = Am / (Am + Bm), wb = Bm / (Am + Bm);
    float4 a1 = *(const float4*)(at1f_in + oi);
    float m0 = wa * a1.x + wb * s[0];
    float m1 = wa * a1.y + wb * s[1];
    float m2 = wa * a1.z + wb * s[2];
    float m3 = wa * a1.w + wb * s[3];
    int gc = h * 128 + c4 * 4;  // global col 0..383
    int st = gc >> 5, lg2 = (gc >> 3) & 3, e0 = gc & 7;
    uint2 pv;
    pv.x = pkh2(m0, m1);
    pv.y = pkh2(m2, m3);
    *(uint2*)(att16_out + (size_t)row * 384 + st * 32 + lg2 * 8 + e0) = pv;
  }
}

// ---- pair scoring v5: f16 gathers (no decode), depth-3 prefetch,
//      f16 MFMA vs LDS-resident f16 linWT, fast-gelu epilogue ----
__global__ __launch_bounds__(1024) void k_pairs(
    const int* __restrict__ aidx, const int* __restrict__ bidx,
    const u16* __restrict__ att16, const u16* __restrict__ linWTh,
    const float* __restrict__ linB, const float* __restrict__ outW,
    const float* __restrict__ outB, const float* __restrict__ embB,
    float* __restrict__ out) {
  __shared__ __align__(16) u16 Wlds[128][392];  // ~100KB, f16
  int t = threadIdx.x, w = t >> 6, l = t & 63;
  int li = l & 15, lg = l >> 4;
  {
    int r = t >> 3, seg = (t & 7) * 48;
    const u16* src = linWTh + (size_t)r * 384 + seg;
    u16* dst = &Wlds[r][seg];
#pragma unroll
    for (int q = 0; q < 6; ++q)
      *(uint4*)(dst + q * 8) = *(const uint4*)(src + q * 8);
  }
  __syncthreads();

  int p0 = blockIdx.x * 512 + w * 32;
  int ia0 = aidx[p0 + li], ib0 = bidx[p0 + li];
  int ia1 = aidx[p0 + 16 + li], ib1 = bidx[p0 + 16 + li];
  const u16* ra0 = att16 + (size_t)ia0 * 384;
  const u16* rb0 = att16 + (size_t)ib0 * 384;
  const u16* ra1 = att16 + (size_t)ia1 * 384;
  const u16* rb1 = att16 + (size_t)ib1 * 384;
  int eoff = lg * 8;

  f32x4 acc[2][8];
#pragma unroll
  for (int g = 0; g < 2; ++g)
#pragma unroll
    for (int nt = 0; nt < 8; ++nt) acc[g][nt] = (f32x4){0.f, 0.f, 0.f, 0.f};

#define LDGH(BUF, S)                                \
  do {                                              \
    int o_ = (S) * 32 + eoff;                       \
    BUF[0] = *(const uint4*)(ra0 + o_);             \
    BUF[1] = *(const uint4*)(rb0 + o_);             \
    BUF[2] = *(const uint4*)(ra1 + o_);             \
    BUF[3] = *(const uint4*)(rb1 + o_);             \
  } while (0)
#define WORKH(BUF, S)                                                        \
  do {                                                                       \
    UH a0_, b0_, a1_, b1_, af0_, af1_;                                       \
    a0_.u = BUF[0]; b0_.u = BUF[1];                                          \
    a1_.u = BUF[2]; b1_.u = BUF[3];                                          \
    af0_.h = a0_.h * b0_.h;                                                  \
    af1_.h = a1_.h * b1_.h;                                                  \
    int j0_ = (S) * 32 + lg * 8;                                             \
    _Pragma("unroll") for (int nt = 0; nt < 8; ++nt) {                       \
      UH bb_;                                                                \
      bb_.u = *(const uint4*)&Wlds[nt * 16 + li][j0_];                       \
      acc[0][nt] = __builtin_amdgcn_mfma_f32_16x16x32_f16(af0_.h, bb_.h,     \
                                                  acc[0][nt], 0, 0, 0);      \
      acc[1][nt] = __builtin_amdgcn_mfma_f32_16x16x32_f16(af1_.h, bb_.h,     \
                                                  acc[1][nt], 0, 0, 0);      \
    }                                                                        \
  } while (0)

  uint4 bX[4], bY[4], bZ[4];
  LDGH(bX, 0);
  LDGH(bY, 1);
  LDGH(bZ, 2);
  WORKH(bX, 0);
  LDGH(bX, 3);
  WORKH(bY, 1);
  LDGH(bY, 4);
  WORKH(bZ, 2);
  LDGH(bZ, 5);
  WORKH(bX, 3);
  LDGH(bX, 6);
  WORKH(bY, 4);
  LDGH(bY, 7);
  WORKH(bZ, 5);
  LDGH(bZ, 8);
  WORKH(bX, 6);
  LDGH(bX, 9);
  WORKH(bY, 7);
  LDGH(bY, 10);
  WORKH(bZ, 8);
  LDGH(bZ, 11);
  WORKH(bX, 9);
  WORKH(bY, 10);
  WORKH(bZ, 11);
#undef LDGH
#undef WORKH

#pragma unroll
  for (int g = 0; g < 2; ++g) {
    float z[4] = {0.f, 0.f, 0.f, 0.f};
#pragma unroll
    for (int nt = 0; nt < 8; ++nt) {
      int f = nt * 16 + li;
      float lb = linB[f], ow = outW[f];
#pragma unroll
      for (int r = 0; r < 4; ++r) {
        float y = geluf(acc[g][nt][r] + lb);
        z[r] = fmaf(y, ow, z[r]);
      }
    }
#pragma unroll
    for (int r = 0; r < 4; ++r) {
      z[r] += __shfl_xor(z[r], 1);
      z[r] += __shfl_xor(z[r], 2);
      z[r] += __shfl_xor(z[r], 4);
      z[r] += __shfl_xor(z[r], 8);
    }
    if (li == 0) {
#pragma unroll
      for (int r = 0; r < 4; ++r) {
        int pi = p0 + g * 16 + lg * 4 + r;
        float badd = geluf(embB[aidx[pi]] + embB[bidx[pi]]);
        float zz = z[r] + badd * outW[128] + outB[0];
        out[pi] = 1.f / (1.f + __expf(-zz));
      }
    }
  }
}

extern "C" void kernel_launch(void* const* d_in, const int* in_sizes, int n_in,
                              void* d_out, int out_size, void* d_ws, size_t ws_size,
                              hipStream_t stream) {
  (void)in_sizes; (void)n_in; (void)out_size; (void)ws_size;
  const int* aidx = (const int*)d_in[0];
  const int* bidx = (const int*)d_in[1];
  const int* adj = (const int*)d_in[2];
  const float* emb = (const float*)d_in[3];
  const float* embB = (const float*)d_in[4];
  const float* W1 = (const float*)d_in[5];
  const float* av1 = (const float*)d_in[6];
  const float* W2 = (const float*)d_in[7];
  const float* av2 = (const float*)d_in[8];
  const float* amix = (const float*)d_in[9];
  const float* bmix = (const float*)d_in[10];
  const float* linW = (const float*)d_in[11];
  const float* linB = (const float*)d_in[12];
  const float* outW = (const float*)d_in[13];
  const float* outB = (const float*)d_in[14];

  char* ws = (char*)d_ws;
  u64* bm = (u64*)(ws + 0);                           // 2MB
  u16* WhTF = (u16*)(ws + (2u << 20));                // 3MB fragment-major f16
  float* E1 = (float*)(ws + (5u << 20));              // 48KB each
  float* F1 = (float*)(ws + (5u << 20) + (64u << 10));
  u16* E2h = (u16*)(ws + (5u << 20) + (128u << 10));  // 24KB f16
  u16* F2h = (u16*)(ws + (5u << 20) + (192u << 10));  // 24KB f16
  u16* linWTh = (u16*)(ws + (5u << 20) + (256u << 10));  // 96KB f16
  u16* WT1 = (u16*)(ws + (5u << 20) + (384u << 10));    // 192KB
  u16* WT2 = (u16*)(ws + (5u << 20) + (640u << 10));    // 288KB
  float* at1f = (float*)(ws + (6u << 20));            // 6MB
  u16* sh12 = (u16*)(ws + (12u << 20));               // 3MB: emb16 -> at1b
  u16* emb16 = sh12;
  u16* at1b = sh12;
  unsigned int* bmF = (unsigned int*)(ws + (15u << 20));  // 2MB
  u16* Pp = (u16*)(ws + (17u << 20));                 // 24MiB bf16 partials
  float* dnP = (float*)(ws + (41u << 20));            // 384KB dn partials
  u16* att16 = (u16*)(ws + (42u << 20));              // 3MB f16 pair table

  k_bitmask<<<NN, 256, 0, stream>>>(adj, bm);
  k_maskf<<<2048, 256, 0, stream>>>(bm, bmF);
  k_prep<<<5248, 256, 0, stream>>>(emb, W1, W2, linW, emb16, WT1, WT2, linWTh);
  k_wh<256><<<dim3(256, NH), 64, 0, stream>>>(emb16, WT1, av1, WhTF, E1, F1, E2h, F2h);
  k_acc<<<dim3(256, NH), 256, 0, stream>>>(bmF, WhTF, E1, F1, E2h, F2h, Pp, dnP);
  k_fin<<<1536, 256, 0, stream>>>(Pp, dnP, at1f, amix, bmix, at1f, at1b, att16, 0);
  k_wh<384><<<dim3(256, NH), 64, 0, stream>>>(at1b, WT2, av2, WhTF, E1, F1, E2h, F2h);
  k_acc<<<dim3(256, NH), 256, 0, stream>>>(bmF, WhTF, E1, F1, E2h, F2h, Pp, dnP);
  k_fin<<<1536, 256, 0, stream>>>(Pp, dnP, at1f, amix, bmix, at1f, at1b, att16, 1);
  k_pairs<<<NPAIR / 512, 1024, 0, stream>>>(aidx, bidx, att16, linWTh, linB, outW,
                                            outB, embB, (float*)d_out);
}

// Round 24
// 152.147 us; speedup vs baseline: 1.0856x; 1.0856x over previous
//
#include <hip/hip_runtime.h>

typedef unsigned long long u64;
typedef unsigned short u16;
typedef __bf16 bf16_t;
typedef bf16_t bf16x8 __attribute__((ext_vector_type(8)));
typedef _Float16 f16_t;
typedef f16_t f16x8 __attribute__((ext_vector_type(8)));
typedef f16_t f16x2 __attribute__((ext_vector_type(2)));
typedef __fp16 h16n_t;
typedef h16n_t h16n2 __attribute__((ext_vector_type(2)));
typedef float f32x4 __attribute__((ext_vector_type(4)));
typedef float f32x2 __attribute__((ext_vector_type(2)));

#define NN 4096
#define NH 3
#define NPAIR 131072
#define LOG2E 1.4426950408889634f

#if __has_builtin(__builtin_amdgcn_cvt_pk_fp8_f32) && \
    __has_builtin(__builtin_amdgcn_cvt_pk_f32_fp8)
#define HAVE_FP8_CVT 1
#else
#define HAVE_FP8_CVT 0
#endif

union U8 { uint4 u; bf16x8 b; };
union UH { uint4 u; f16x8 h; };
union UH2 { f16x2 h; unsigned int u; };
union UHN2 { h16n2 h; unsigned int u; };

__device__ __forceinline__ u16 f2us(float f) {
  unsigned int x = __float_as_uint(f);
  x = x + 0x7fffu + ((x >> 16) & 1u);
  return (u16)(x >> 16);
}
__device__ __forceinline__ float us2f(u16 u) {
  return __uint_as_float(((unsigned int)u) << 16);
}
__device__ __forceinline__ unsigned int pk2(float a, float b) {
  return (unsigned int)f2us(a) | ((unsigned int)f2us(b) << 16);
}
__device__ __forceinline__ unsigned int pkh2(float a, float b) {
#if __has_builtin(__builtin_amdgcn_cvt_pkrtz)
  UHN2 cv;
  cv.h = __builtin_amdgcn_cvt_pkrtz(a, b);
  return cv.u;
#else
  UH2 cv;
  cv.h[0] = (f16_t)a;
  cv.h[1] = (f16_t)b;
  return cv.u;
#endif
}
__device__ __forceinline__ u16 f2h16(float a) {
  UH2 cv;
  cv.h[0] = (f16_t)a;
  cv.h[1] = (f16_t)0.f;
  return (u16)(cv.u & 0xffffu);
}
__device__ __forceinline__ f16x2 h2max(f16x2 a, f16x2 b) {
  f16x2 r;
  r[0] = a[0] > b[0] ? a[0] : b[0];
  r[1] = a[1] > b[1] ? a[1] : b[1];
  return r;
}
__device__ __forceinline__ float exp2fast(float x) {
#if __has_builtin(__builtin_amdgcn_exp2f)
  return __builtin_amdgcn_exp2f(x);
#else
  return __expf(x * 0.6931471805599453f);
#endif
}
// A&S 7.1.26 erf approx, |err| <= 1.5e-7 (abs)
__device__ __forceinline__ float erf_fast(float x) {
  float ax = fabsf(x);
  float t = 1.f / fmaf(0.3275911f, ax, 1.f);
  float poly =
      t * (0.254829592f +
           t * (-0.284496736f +
                t * (1.421413741f +
                     t * (-1.453152027f + t * 1.061405429f))));
  float e = exp2fast(-ax * ax * LOG2E);
  float r = 1.f - poly * e;
  return x < 0.f ? -r : r;
}
__device__ __forceinline__ float geluf(float x) {
  return 0.5f * x * (1.f + erf_fast(x * 0.70710678118654752f));
}
__device__ __forceinline__ void gl_lds16(const u16* g, u16* s) {
  __builtin_amdgcn_global_load_lds(
      (const __attribute__((address_space(1))) unsigned int*)g,
      (__attribute__((address_space(3))) unsigned int*)s, 16, 0, 0);
}

#if !HAVE_FP8_CVT
__device__ __forceinline__ float e4m3_f(unsigned int b) {
  unsigned int s = b >> 7, e = (b >> 3) & 15, m = b & 7;
  float v = (e == 0) ? (float)m * 0.001953125f
                     : __uint_as_float(((e + 120u) << 23) | (m << 20));
  return s ? -v : v;
}
__device__ __forceinline__ unsigned int f_e4m3(float f) {
  unsigned int sign = (__float_as_uint(f) >> 24) & 0x80u;
  float a = fabsf(f);
  if (!(a >= 9.765625e-4f)) return sign;
  a = fminf(a, 448.f);
  int e;
  float fr = frexpf(a, &e);
  if (e >= -5) {
    int M = (int)(fr * 16.f + 0.5f);
    int E = e + 6;
    if (M == 16) { M = 8; E += 1; }
    if (E > 15) { E = 15; M = 15; }
    return sign | (unsigned)(E << 3) | (unsigned)(M - 8);
  }
  int M = (int)(a * 512.f + 0.5f);
  if (M > 7) M = 7;
  return sign | (unsigned)M;
}
#endif

__device__ __forceinline__ void dec8lo(uint4 u, float* o) {
#if HAVE_FP8_CVT
  f32x2 p0 = __builtin_amdgcn_cvt_pk_f32_fp8((int)u.x, false);
  f32x2 p1 = __builtin_amdgcn_cvt_pk_f32_fp8((int)u.x, true);
  f32x2 p2 = __builtin_amdgcn_cvt_pk_f32_fp8((int)u.y, false);
  f32x2 p3 = __builtin_amdgcn_cvt_pk_f32_fp8((int)u.y, true);
  o[0] = p0[0]; o[1] = p0[1]; o[2] = p1[0]; o[3] = p1[1];
  o[4] = p2[0]; o[5] = p2[1]; o[6] = p3[0]; o[7] = p3[1];
#else
#pragma unroll
  for (int e = 0; e < 4; ++e) o[e] = e4m3_f((u.x >> (8 * e)) & 0xffu);
#pragma unroll
  for (int e = 0; e < 4; ++e) o[4 + e] = e4m3_f((u.y >> (8 * e)) & 0xffu);
#endif
}
__device__ __forceinline__ void dec8hi(uint4 u, float* o) {
#if HAVE_FP8_CVT
  f32x2 p0 = __builtin_amdgcn_cvt_pk_f32_fp8((int)u.z, false);
  f32x2 p1 = __builtin_amdgcn_cvt_pk_f32_fp8((int)u.z, true);
  f32x2 p2 = __builtin_amdgcn_cvt_pk_f32_fp8((int)u.w, false);
  f32x2 p3 = __builtin_amdgcn_cvt_pk_f32_fp8((int)u.w, true);
  o[0] = p0[0]; o[1] = p0[1]; o[2] = p1[0]; o[3] = p1[1];
  o[4] = p2[0]; o[5] = p2[1]; o[6] = p3[0]; o[7] = p3[1];
#else
#pragma unroll
  for (int e = 0; e < 4; ++e) o[e] = e4m3_f((u.z >> (8 * e)) & 0xffu);
#pragma unroll
  for (int e = 0; e < 4; ++e) o[4 + e] = e4m3_f((u.w >> (8 * e)) & 0xffu);
#endif
}

// ---- adj int32 [N][N] -> bitmask u64 [N][N/64] (4096 blocks, streaming) ----
__global__ __launch_bounds__(256) void k_bitmask(const int* __restrict__ adj,
                                                 u64* __restrict__ bm) {
  int i = blockIdx.x;
  int lane = threadIdx.x & 63;
  int wv = threadIdx.x >> 6;
  const int* row = adj + (size_t)i * NN;
  for (int wq = wv; wq < NN / 64; wq += 4) {
    u64 b = __ballot(row[wq * 64 + lane] > 0);
    if (lane == 0) bm[(size_t)i * (NN / 64) + wq] = b;
  }
}

// ---- fragment-major mask: bmF[ib(64)][jc(128)][lane(64)] u32 = 4 m-bytes ----
__global__ __launch_bounds__(256) void k_maskf(const u64* __restrict__ bm,
                                               unsigned int* __restrict__ bmF) {
  int idx = blockIdx.x * 256 + threadIdx.x;  // 524288 total
  int l = idx & 63, jc = (idx >> 6) & 127, ib = idx >> 13;
  int li = l & 15, lg = l >> 4;
  const unsigned char* b8 = (const unsigned char*)bm;
  unsigned int v = 0;
#pragma unroll
  for (int m = 0; m < 4; ++m)
    v |= (unsigned int)b8[(size_t)(ib * 64 + m * 16 + li) * 512 + jc * 4 + lg]
         << (8 * m);
  bmF[idx] = v;
}

// ---- bf16 tables ----
__global__ __launch_bounds__(256) void k_prep(
    const float* __restrict__ emb, const float* __restrict__ W1,
    const float* __restrict__ W2, const float* __restrict__ linW,
    u16* __restrict__ emb16, u16* __restrict__ WT1, u16* __restrict__ WT2,
    u16* __restrict__ linWT) {
  int idx = blockIdx.x * 256 + threadIdx.x;
  if (idx < 1048576) { emb16[idx] = f2us(emb[idx]); return; }
  idx -= 1048576;
  if (idx < 98304) {
    int h = idx / 32768, r = idx & 32767, f = r >> 8, k = r & 255;
    WT1[idx] = f2us(W1[h * 32768 + k * 128 + f]);
    return;
  }
  idx -= 98304;
  if (idx < 147456) {
    int h = idx / 49152, r = idx % 49152, f = r / 384, k = r % 384;
    WT2[idx] = f2us(W2[h * 49152 + k * 128 + f]);
    return;
  }
  idx -= 147456;
  if (idx < 49152) {
    int f = idx / 384, k = idx % 384;
    linWT[idx] = f2us(linW[k * 128 + f]);
  }
}

// ---- Wh = x @ W via MFMA, v2: x-row loaded upfront, 3-deep register B
//      prefetch, fully unrolled (all static indices); 1 wave / 16 rows ----
template <int K>
__global__ __launch_bounds__(64, 2) void k_wh(const u16* __restrict__ xb,
                                              const u16* __restrict__ WT,
                                              const float* __restrict__ av,
                                              u16* __restrict__ WhTF,
                                              float* __restrict__ E1,
                                              float* __restrict__ F1,
                                              u16* __restrict__ E2h,
                                              u16* __restrict__ F2h) {
  constexpr int NS = K / 32;
  int h = blockIdx.y, l = threadIdx.x, li = l & 15, lg = l >> 4;
  int iw = blockIdx.x * 16;
  const u16* Wb = WT + (size_t)h * 128 * K;
  const u16* xr = xb + (size_t)(iw + li) * K;

  f32x4 acc[8];
#pragma unroll
  for (int nt = 0; nt < 8; ++nt) acc[nt] = (f32x4){0.f, 0.f, 0.f, 0.f};

  uint4 xa[NS];
#pragma unroll
  for (int s = 0; s < NS; ++s)
    xa[s] = *(const uint4*)(xr + s * 32 + lg * 8);

  uint4 bbuf[3][8];
#define LDB(S)                                                               \
  do {                                                                       \
    _Pragma("unroll") for (int nt = 0; nt < 8; ++nt)                         \
        bbuf[(S) % 3][nt] = *(const uint4*)(Wb + (size_t)(nt * 16 + li) * K +\
                                            (S) * 32 + lg * 8);              \
  } while (0)

#pragma unroll
  for (int pf = 0; pf < 3; ++pf) {
    if (pf < NS) LDB(pf);
  }
#pragma unroll
  for (int s = 0; s < NS; ++s) {
    U8 af;
    af.u = xa[s];
#pragma unroll
    for (int nt = 0; nt < 8; ++nt) {
      U8 bb;
      bb.u = bbuf[s % 3][nt];
      acc[nt] = __builtin_amdgcn_mfma_f32_16x16x32_bf16(af.b, bb.b, acc[nt], 0, 0, 0);
    }
    if (s + 3 < NS) LDB(s + 3);
  }
#undef LDB

  float p1[4] = {0.f, 0.f, 0.f, 0.f}, p2[4] = {0.f, 0.f, 0.f, 0.f};
#pragma unroll
  for (int nt = 0; nt < 8; ++nt) {
    float a1 = av[h * 256 + nt * 16 + li];
    float a2 = av[h * 256 + 128 + nt * 16 + li];
#pragma unroll
    for (int r = 0; r < 4; ++r) {
      p1[r] = fmaf(acc[nt][r], a1, p1[r]);
      p2[r] = fmaf(acc[nt][r], a2, p2[r]);
    }
  }
#pragma unroll
  for (int r = 0; r < 4; ++r) {
#pragma unroll
    for (int o = 1; o < 16; o <<= 1) {
      p1[r] += __shfl_xor(p1[r], o);
      p2[r] += __shfl_xor(p2[r], o);
    }
  }
  if (li == 0) {
#pragma unroll
    for (int r = 0; r < 4; ++r) {
      int idx = h * NN + iw + lg * 4 + r;
      float s1L = p1[r] * LOG2E, s2L = p2[r] * LOG2E;
      E1[idx] = exp2fast(s1L);
      F1[idx] = exp2fast(0.2f * s1L);
      E2h[idx] = f2h16(exp2fast(s2L));
      F2h[idx] = f2h16(exp2fast(0.2f * s2L));
    }
  }
  // fragment-major f16 write
  u16* Wo = WhTF + (size_t)h * 524288;
  int jc = iw >> 5, jin = (iw & 31) + lg * 4;
#pragma unroll
  for (int nt = 0; nt < 8; ++nt) {
    uint2 pw;
    pw.x = pkh2(acc[nt][0], acc[nt][1]);
    pw.y = pkh2(acc[nt][2], acc[nt][3]);
    *(uint2*)(Wo + (size_t)nt * 65536 + (size_t)jc * 512 + li * 32 + jin) = pw;
  }
}

// ---- attention accumulate v8 (f16): 4-wave/256-thr blocks, wave = M=32 x
//      N=128 x K=512 (kq=8); grid 32x8x3 = 768 = 3 blocks/CU; counted
//      vmcnt(2) pipeline; packed-f16 p-compute; f16 MFMA; T5 setprio ----
#define WAITC(N)                                                  \
  do {                                                            \
    asm volatile("s_waitcnt vmcnt(" #N ")" ::: "memory");         \
    __builtin_amdgcn_sched_barrier(0);                            \
    __builtin_amdgcn_s_barrier();                                 \
    __builtin_amdgcn_sched_barrier(0);                            \
  } while (0)
#define ROT3(X) X = (X == 2) ? 0 : X + 1

__global__ __launch_bounds__(256, 3) void k_acc(
    const unsigned int* __restrict__ bmF, const u16* __restrict__ WhTF,
    const float* __restrict__ E1, const float* __restrict__ F1,
    const u16* __restrict__ E2h, const u16* __restrict__ F2h,
    u16* __restrict__ Pp, float* __restrict__ dnP) {
  __shared__ __align__(16) u16 Bl[3][4096];  // 3 x 8KB
  int h = blockIdx.y, t = threadIdx.x, w = t >> 6, l = t & 63;
  int li = l & 15, lg = l >> 4;
  int rt = blockIdx.x >> 3, kq = blockIdx.x & 7;  // 32 rt x 8 kq
  int iw0 = rt * 128 + w * 32;
  int k0 = kq * 512;
  int perm = (l & 15) * 4 + (l >> 4);
  const u16* gsrcA = WhTF + (size_t)h * 524288 + (size_t)w * 65536 +
                     (size_t)(k0 >> 5) * 512 + perm * 8;
  const u16* gsrcB = gsrcA + (size_t)4 * 65536;
  const u16* E2p = E2h + h * NN;
  const u16* F2p = F2h + h * NN;
  f16x2 e1h[2], f1h[2];
#pragma unroll
  for (int mg = 0; mg < 2; ++mg) {
    f16_t e1 = (f16_t)E1[h * NN + iw0 + mg * 16 + li];
    f16_t f1 = (f16_t)F1[h * NN + iw0 + mg * 16 + li];
    e1h[mg][0] = e1; e1h[mg][1] = e1;
    f1h[mg][0] = f1; f1h[mg][1] = f1;
  }
  int mq0 = (iw0 >> 4) & 3;
  const unsigned int* mrow =
      bmF + ((size_t)(iw0 >> 6) * 128 + (k0 >> 5)) * 64 + l;

  f32x4 acc[2][8];
  f32x4 accD[2];
#pragma unroll
  for (int mg = 0; mg < 2; ++mg) {
    accD[mg] = (f32x4){0.f, 0.f, 0.f, 0.f};
#pragma unroll
    for (int nt = 0; nt < 8; ++nt) acc[mg][nt] = (f32x4){0.f, 0.f, 0.f, 0.f};
  }
  UH ones;
  ones.u = make_uint4(0x3C003C00u, 0x3C003C00u, 0x3C003C00u, 0x3C003C00u);

#define STG2(B, S)                                        \
  do {                                                    \
    gl_lds16(gsrcA + (size_t)(S) * 512, &Bl[B][w * 512]); \
    gl_lds16(gsrcB + (size_t)(S) * 512, &Bl[B][(w + 4) * 512]); \
  } while (0)
#define LDSC(SUF, S)                                      \
  do {                                                    \
    int j0_ = k0 + (S) * 32;                              \
    mw##SUF = mrow[(S) * 64];                             \
    Eu##SUF = *(const uint4*)(E2p + j0_ + lg * 8);        \
    Fu##SUF = *(const uint4*)(F2p + j0_ + lg * 8);        \
  } while (0)
#define BODY(SUF)                                                            \
  do {                                                                       \
    unsigned int ew_[4] = {Eu##SUF.x, Eu##SUF.y, Eu##SUF.z, Eu##SUF.w};      \
    unsigned int fw_[4] = {Fu##SUF.x, Fu##SUF.y, Fu##SUF.z, Fu##SUF.w};      \
    UH A_[2];                                                                \
    _Pragma("unroll") for (int mg = 0; mg < 2; ++mg) {                       \
      unsigned int mb_ = (mw##SUF >> (8 * (mq0 + mg))) & 0xffu;              \
      unsigned int aw_[4];                                                   \
      _Pragma("unroll") for (int q = 0; q < 4; ++q) {                        \
        UH2 eh_, fh_, ph_;                                                   \
        eh_.u = ew_[q];                                                      \
        fh_.u = fw_[q];                                                      \
        ph_.h = h2max(e1h[mg] * eh_.h, f1h[mg] * fh_.h);                     \
        unsigned int sel_ = (((mb_ >> (2 * q)) & 1u) ? 0xFFFFu : 0u) |       \
                            (((mb_ >> (2 * q + 1)) & 1u) ? 0xFFFF0000u : 0u);\
        aw_[q] = ph_.u & sel_;                                               \
      }                                                                      \
      A_[mg].u = make_uint4(aw_[0], aw_[1], aw_[2], aw_[3]);                 \
    }                                                                        \
    const u16* bl_ = &Bl[bcur][0] + l * 8;                                   \
    __builtin_amdgcn_s_setprio(1);                                           \
    _Pragma("unroll") for (int nt = 0; nt < 8; ++nt) {                       \
      UH B_;                                                                 \
      B_.u = *(const uint4*)(bl_ + nt * 512);                                \
      acc[0][nt] = __builtin_amdgcn_mfma_f32_16x16x32_f16(A_[0].h, B_.h,     \
                                                  acc[0][nt], 0, 0, 0);      \
      acc[1][nt] = __builtin_amdgcn_mfma_f32_16x16x32_f16(A_[1].h, B_.h,     \
                                                  acc[1][nt], 0, 0, 0);      \
    }                                                                        \
    accD[0] = __builtin_amdgcn_mfma_f32_16x16x32_f16(A_[0].h, ones.h,        \
                                                     accD[0], 0, 0, 0);      \
    accD[1] = __builtin_amdgcn_mfma_f32_16x16x32_f16(A_[1].h, ones.h,        \
                                                     accD[1], 0, 0, 0);      \
    __builtin_amdgcn_s_setprio(0);                                           \
    ROT3(bcur);                                                              \
  } while (0)

  unsigned int mwA, mwB;
  uint4 EuA, FuA, EuB, FuB;
  int bcur = 0, bstg = 2;
  LDSC(A, 0);
  STG2(0, 0);
  STG2(1, 1);
#pragma unroll 1
  for (int s = 0; s < 16; s += 2) {
    WAITC(2);
    LDSC(B, s + 1);
    if (s + 2 < 16) { STG2(bstg, s + 2); ROT3(bstg); }
    BODY(A);
    if (s + 1 == 15) { WAITC(0); } else { WAITC(2); }
    if (s + 2 < 16) LDSC(A, s + 2);
    if (s + 3 < 16) { STG2(bstg, s + 3); ROT3(bstg); }
    BODY(B);
  }
#undef STG2
#undef LDSC
#undef BODY

#pragma unroll
  for (int mg = 0; mg < 2; ++mg) {
    size_t rbase = (size_t)(kq * 3 + h) * NN + iw0 + mg * 16;
#pragma unroll
    for (int nt = 0; nt < 8; ++nt)
#pragma unroll
      for (int r = 0; r < 4; ++r)
        Pp[(rbase + lg * 4 + r) * 128 + nt * 16 + li] = f2us(acc[mg][nt][r]);
    if (li == 0) {
#pragma unroll
      for (int r = 0; r < 4; ++r)
        dnP[rbase + lg * 4 + r] = accD[mg][r];
    }
  }
}

// ---- finalize: sum 8 bf16 K-chunk partials, /dn, ELU, mix; mode1 -> fp8
//      pair-table att8 in 2-step-packed layout ----
__global__ __launch_bounds__(256) void k_fin(
    const u16* __restrict__ Pp, const float* __restrict__ dnP,
    const float* __restrict__ at1f_in, const float* __restrict__ amix,
    const float* __restrict__ bmix, float* __restrict__ at1f_out,
    u16* __restrict__ at1b_out, unsigned char* __restrict__ att8_out,
    int mode) {
  int gid = blockIdx.x * 256 + threadIdx.x;
  int c4 = gid & 31, row = (gid >> 5) & 4095, h = gid >> 17;
  size_t off = ((size_t)h * NN + row) * 128 + c4 * 4;
  const size_t ks = (size_t)3 * NN * 128;
  float s[4] = {0.f, 0.f, 0.f, 0.f};
  float dsum = 0.f;
#pragma unroll
  for (int q = 0; q < 8; ++q) {
    uint2 v = *(const uint2*)(Pp + q * ks + off);
    s[0] += us2f((u16)(v.x & 0xffffu));
    s[1] += us2f((u16)(v.x >> 16));
    s[2] += us2f((u16)(v.y & 0xffffu));
    s[3] += us2f((u16)(v.y >> 16));
    dsum += dnP[(size_t)(q * 3 + h) * NN + row];
  }
  float inv = 1.f / fmaxf(dsum, 1e-30f);
#pragma unroll
  for (int q = 0; q < 4; ++q) {
    s[q] *= inv;
    s[q] = s[q] > 0.f ? s[q] : (exp2fast(s[q] * LOG2E) - 1.f);
  }
  size_t oi = (size_t)row * 384 + h * 128 + c4 * 4;
  if (mode == 0) {
    *(float4*)(at1f_out + oi) = make_float4(s[0], s[1], s[2], s[3]);
    uint2 pb;
    pb.x = pk2(s[0], s[1]);
    pb.y = pk2(s[2], s[3]);
    *(uint2*)(at1b_out + oi) = pb;
  } else {
    float Am = amix[0], Bm = bmix[0];
    float wa = Am / (Am + Bm), wb = Bm / (Am + Bm);
    float4 a1 = *(const float4*)(at1f_in + oi);
    float m0 = wa * a1.x + wb * s[0];
    float m1 = wa * a1.y + wb * s[1];
    float m2 = wa * a1.z + wb * s[2];
    float m3 = wa * a1.w + wb * s[3];
#if HAVE_FP8_CVT
    int v8 = __builtin_amdgcn_cvt_pk_fp8_f32(m0, m1, 0, false);
    v8 = __builtin_amdgcn_cvt_pk_fp8_f32(m2, m3, v8, true);
#else
    unsigned int v8 = f_e4m3(m0) | (f_e4m3(m1) << 8) | (f_e4m3(m2) << 16) |
                      (f_e4m3(m3) << 24);
#endif
    int gc = h * 128 + c4 * 4;  // global col 0..383
    int st = gc >> 5, lg2 = (gc >> 3) & 3, e0 = gc & 7;
    int kp = (st >> 1) * 64 + lg2 * 16 + (st & 1) * 8 + e0;
    *(unsigned int*)(att8_out + (size_t)row * 384 + kp) = (unsigned int)v8;
  }
}

// ---- pair scoring v4: fp8 gathers, depth-3 prefetch, fast-gelu epilogue ----
__global__ __launch_bounds__(1024) void k_pairs(
    const int* __restrict__ aidx, const int* __restrict__ bidx,
    const unsigned char* __restrict__ att8, const u16* __restrict__ linWT,
    const float* __restrict__ linB, const float* __restrict__ outW,
    const float* __restrict__ outB, const float* __restrict__ embB,
    float* __restrict__ out) {
  __shared__ __align__(16) u16 Wlds[128][392];  // ~100KB
  int t = threadIdx.x, w = t >> 6, l = t & 63;
  int li = l & 15, lg = l >> 4;
  {
    int r = t >> 3, seg = (t & 7) * 48;
    const u16* src = linWT + (size_t)r * 384 + seg;
    u16* dst = &Wlds[r][seg];
#pragma unroll
    for (int q = 0; q < 6; ++q)
      *(uint4*)(dst + q * 8) = *(const uint4*)(src + q * 8);
  }
  __syncthreads();

  int p0 = blockIdx.x * 512 + w * 32;
  int ia0 = aidx[p0 + li], ib0 = bidx[p0 + li];
  int ia1 = aidx[p0 + 16 + li], ib1 = bidx[p0 + 16 + li];
  const unsigned char* ra0 = att8 + (size_t)ia0 * 384;
  const unsigned char* rb0 = att8 + (size_t)ib0 * 384;
  const unsigned char* ra1 = att8 + (size_t)ia1 * 384;
  const unsigned char* rb1 = att8 + (size_t)ib1 * 384;
  int boff = lg * 16;

  f32x4 acc[2][8];
#pragma unroll
  for (int g = 0; g < 2; ++g)
#pragma unroll
    for (int nt = 0; nt < 8; ++nt) acc[g][nt] = (f32x4){0.f, 0.f, 0.f, 0.f};

#define LDG8(BUF, S2)                               \
  do {                                              \
    int o_ = (S2) * 64 + boff;                      \
    BUF[0] = *(const uint4*)(ra0 + o_);             \
    BUF[1] = *(const uint4*)(rb0 + o_);             \
    BUF[2] = *(const uint4*)(ra1 + o_);             \
    BUF[3] = *(const uint4*)(rb1 + o_);             \
  } while (0)
#define WORK8(BUF, S2)                                                       \
  do {                                                                       \
    _Pragma("unroll") for (int hf = 0; hf < 2; ++hf) {                       \
      float a0_[8], b0_[8], a1_[8], b1_[8];                                  \
      if (hf == 0) {                                                         \
        dec8lo(BUF[0], a0_); dec8lo(BUF[1], b0_);                            \
        dec8lo(BUF[2], a1_); dec8lo(BUF[3], b1_);                            \
      } else {                                                               \
        dec8hi(BUF[0], a0_); dec8hi(BUF[1], b0_);                            \
        dec8hi(BUF[2], a1_); dec8hi(BUF[3], b1_);                            \
      }                                                                      \
      U8 af0_, af1_;                                                         \
      _Pragma("unroll") for (int e = 0; e < 8; ++e) {                        \
        af0_.b[e] = (bf16_t)(a0_[e] * b0_[e]);                               \
        af1_.b[e] = (bf16_t)(a1_[e] * b1_[e]);                               \
      }                                                                      \
      int j0_ = ((S2) * 2 + hf) * 32 + lg * 8;                               \
      _Pragma("unroll") for (int nt = 0; nt < 8; ++nt) {                     \
        U8 bb_;                                                              \
        bb_.u = *(const uint4*)&Wlds[nt * 16 + li][j0_];                     \
        acc[0][nt] = __builtin_amdgcn_mfma_f32_16x16x32_bf16(af0_.b, bb_.b,  \
                                                    acc[0][nt], 0, 0, 0);    \
        acc[1][nt] = __builtin_amdgcn_mfma_f32_16x16x32_bf16(af1_.b, bb_.b,  \
                                                    acc[1][nt], 0, 0, 0);    \
      }                                                                      \
    }                                                                        \
  } while (0)

  uint4 bX[4], bY[4], bZ[4];
  LDG8(bX, 0);
  LDG8(bY, 1);
  LDG8(bZ, 2);
  WORK8(bX, 0);
  LDG8(bX, 3);
  WORK8(bY, 1);
  LDG8(bY, 4);
  WORK8(bZ, 2);
  LDG8(bZ, 5);
  WORK8(bX, 3);
  WORK8(bY, 4);
  WORK8(bZ, 5);
#undef LDG8
#undef WORK8

#pragma unroll
  for (int g = 0; g < 2; ++g) {
    float z[4] = {0.f, 0.f, 0.f, 0.f};
#pragma unroll
    for (int nt = 0; nt < 8; ++nt) {
      int f = nt * 16 + li;
      float lb = linB[f], ow = outW[f];
#pragma unroll
      for (int r = 0; r < 4; ++r) {
        float y = geluf(acc[g][nt][r] + lb);
        z[r] = fmaf(y, ow, z[r]);
      }
    }
#pragma unroll
    for (int r = 0; r < 4; ++r) {
      z[r] += __shfl_xor(z[r], 1);
      z[r] += __shfl_xor(z[r], 2);
      z[r] += __shfl_xor(z[r], 4);
      z[r] += __shfl_xor(z[r], 8);
    }
    if (li == 0) {
#pragma unroll
      for (int r = 0; r < 4; ++r) {
        int pi = p0 + g * 16 + lg * 4 + r;
        float badd = geluf(embB[aidx[pi]] + embB[bidx[pi]]);
        float zz = z[r] + badd * outW[128] + outB[0];
        out[pi] = 1.f / (1.f + __expf(-zz));
      }
    }
  }
}

extern "C" void kernel_launch(void* const* d_in, const int* in_sizes, int n_in,
                              void* d_out, int out_size, void* d_ws, size_t ws_size,
                              hipStream_t stream) {
  (void)in_sizes; (void)n_in; (void)out_size; (void)ws_size;
  const int* aidx = (const int*)d_in[0];
  const int* bidx = (const int*)d_in[1];
  const int* adj = (const int*)d_in[2];
  const float* emb = (const float*)d_in[3];
  const float* embB = (const float*)d_in[4];
  const float* W1 = (const float*)d_in[5];
  const float* av1 = (const float*)d_in[6];
  const float* W2 = (const float*)d_in[7];
  const float* av2 = (const float*)d_in[8];
  const float* amix = (const float*)d_in[9];
  const float* bmix = (const float*)d_in[10];
  const float* linW = (const float*)d_in[11];
  const float* linB = (const float*)d_in[12];
  const float* outW = (const float*)d_in[13];
  const float* outB = (const float*)d_in[14];

  char* ws = (char*)d_ws;
  u64* bm = (u64*)(ws + 0);                           // 2MB
  u16* WhTF = (u16*)(ws + (2u << 20));                // 3MB fragment-major f16
  float* E1 = (float*)(ws + (5u << 20));              // 48KB each
  float* F1 = (float*)(ws + (5u << 20) + (64u << 10));
  u16* E2h = (u16*)(ws + (5u << 20) + (128u << 10));  // 24KB f16
  u16* F2h = (u16*)(ws + (5u << 20) + (192u << 10));  // 24KB f16
  u16* linWT = (u16*)(ws + (5u << 20) + (256u << 10));  // 96KB
  u16* WT1 = (u16*)(ws + (5u << 20) + (384u << 10));    // 192KB
  u16* WT2 = (u16*)(ws + (5u << 20) + (640u << 10));    // 288KB
  float* at1f = (float*)(ws + (6u << 20));            // 6MB
  u16* sh12 = (u16*)(ws + (12u << 20));               // 3MB: emb16 -> at1b
  u16* emb16 = sh12;
  u16* at1b = sh12;
  unsigned int* bmF = (unsigned int*)(ws + (15u << 20));  // 2MB
  u16* Pp = (u16*)(ws + (17u << 20));                 // 24MiB bf16 partials
  float* dnP = (float*)(ws + (41u << 20));            // 384KB dn partials
  unsigned char* att8 = (unsigned char*)(ws + (42u << 20));  // 1.5MB fp8 table

  k_bitmask<<<NN, 256, 0, stream>>>(adj, bm);
  k_maskf<<<2048, 256, 0, stream>>>(bm, bmF);
  k_prep<<<5248, 256, 0, stream>>>(emb, W1, W2, linW, emb16, WT1, WT2, linWT);
  k_wh<256><<<dim3(256, NH), 64, 0, stream>>>(emb16, WT1, av1, WhTF, E1, F1, E2h, F2h);
  k_acc<<<dim3(256, NH), 256, 0, stream>>>(bmF, WhTF, E1, F1, E2h, F2h, Pp, dnP);
  k_fin<<<1536, 256, 0, stream>>>(Pp, dnP, at1f, amix, bmix, at1f, at1b, att8, 0);
  k_wh<384><<<dim3(256, NH), 64, 0, stream>>>(at1b, WT2, av2, WhTF, E1, F1, E2h, F2h);
  k_acc<<<dim3(256, NH), 256, 0, stream>>>(bmF, WhTF, E1, F1, E2h, F2h, Pp, dnP);
  k_fin<<<1536, 256, 0, stream>>>(Pp, dnP, at1f, amix, bmix, at1f, at1b, att8, 1);
  k_pairs<<<NPAIR / 512, 1024, 0, stream>>>(aidx, bidx, att8, linWT, linB, outW,
                                            outB, embB, (float*)d_out);
}

// Round 25
// 149.381 us; speedup vs baseline: 1.1057x; 1.0185x over previous
//
#include <hip/hip_runtime.h>

typedef unsigned long long u64;
typedef unsigned short u16;
typedef __bf16 bf16_t;
typedef bf16_t bf16x8 __attribute__((ext_vector_type(8)));
typedef _Float16 f16_t;
typedef f16_t f16x8 __attribute__((ext_vector_type(8)));
typedef f16_t f16x2 __attribute__((ext_vector_type(2)));
typedef __fp16 h16n_t;
typedef h16n_t h16n2 __attribute__((ext_vector_type(2)));
typedef float f32x4 __attribute__((ext_vector_type(4)));
typedef float f32x2 __attribute__((ext_vector_type(2)));

#define NN 4096
#define NH 3
#define NPAIR 131072
#define LOG2E 1.4426950408889634f

#if __has_builtin(__builtin_amdgcn_cvt_pk_fp8_f32) && \
    __has_builtin(__builtin_amdgcn_cvt_pk_f32_fp8)
#define HAVE_FP8_CVT 1
#else
#define HAVE_FP8_CVT 0
#endif

union U8 { uint4 u; bf16x8 b; };
union UH { uint4 u; f16x8 h; };
union UH2 { f16x2 h; unsigned int u; };
union UHN2 { h16n2 h; unsigned int u; };

__device__ __forceinline__ u16 f2us(float f) {
  unsigned int x = __float_as_uint(f);
  x = x + 0x7fffu + ((x >> 16) & 1u);
  return (u16)(x >> 16);
}
__device__ __forceinline__ float us2f(u16 u) {
  return __uint_as_float(((unsigned int)u) << 16);
}
__device__ __forceinline__ unsigned int pk2(float a, float b) {
  return (unsigned int)f2us(a) | ((unsigned int)f2us(b) << 16);
}
__device__ __forceinline__ unsigned int pkh2(float a, float b) {
#if __has_builtin(__builtin_amdgcn_cvt_pkrtz)
  UHN2 cv;
  cv.h = __builtin_amdgcn_cvt_pkrtz(a, b);
  return cv.u;
#else
  UH2 cv;
  cv.h[0] = (f16_t)a;
  cv.h[1] = (f16_t)b;
  return cv.u;
#endif
}
__device__ __forceinline__ u16 f2h16(float a) {
  UH2 cv;
  cv.h[0] = (f16_t)a;
  cv.h[1] = (f16_t)0.f;
  return (u16)(cv.u & 0xffffu);
}
__device__ __forceinline__ f16x2 h2max(f16x2 a, f16x2 b) {
  f16x2 r;
  r[0] = a[0] > b[0] ? a[0] : b[0];
  r[1] = a[1] > b[1] ? a[1] : b[1];
  return r;
}
__device__ __forceinline__ float exp2fast(float x) {
#if __has_builtin(__builtin_amdgcn_exp2f)
  return __builtin_amdgcn_exp2f(x);
#else
  return __expf(x * 0.6931471805599453f);
#endif
}
// A&S 7.1.26 erf approx, |err| <= 1.5e-7 (abs)
__device__ __forceinline__ float erf_fast(float x) {
  float ax = fabsf(x);
  float t = 1.f / fmaf(0.3275911f, ax, 1.f);
  float poly =
      t * (0.254829592f +
           t * (-0.284496736f +
                t * (1.421413741f +
                     t * (-1.453152027f + t * 1.061405429f))));
  float e = exp2fast(-ax * ax * LOG2E);
  float r = 1.f - poly * e;
  return x < 0.f ? -r : r;
}
__device__ __forceinline__ float geluf(float x) {
  return 0.5f * x * (1.f + erf_fast(x * 0.70710678118654752f));
}
__device__ __forceinline__ void gl_lds16(const u16* g, u16* s) {
  __builtin_amdgcn_global_load_lds(
      (const __attribute__((address_space(1))) unsigned int*)g,
      (__attribute__((address_space(3))) unsigned int*)s, 16, 0, 0);
}

#if !HAVE_FP8_CVT
__device__ __forceinline__ float e4m3_f(unsigned int b) {
  unsigned int s = b >> 7, e = (b >> 3) & 15, m = b & 7;
  float v = (e == 0) ? (float)m * 0.001953125f
                     : __uint_as_float(((e + 120u) << 23) | (m << 20));
  return s ? -v : v;
}
__device__ __forceinline__ unsigned int f_e4m3(float f) {
  unsigned int sign = (__float_as_uint(f) >> 24) & 0x80u;
  float a = fabsf(f);
  if (!(a >= 9.765625e-4f)) return sign;
  a = fminf(a, 448.f);
  int e;
  float fr = frexpf(a, &e);
  if (e >= -5) {
    int M = (int)(fr * 16.f + 0.5f);
    int E = e + 6;
    if (M == 16) { M = 8; E += 1; }
    if (E > 15) { E = 15; M = 15; }
    return sign | (unsigned)(E << 3) | (unsigned)(M - 8);
  }
  int M = (int)(a * 512.f + 0.5f);
  if (M > 7) M = 7;
  return sign | (unsigned)M;
}
#endif

__device__ __forceinline__ void dec8lo(uint4 u, float* o) {
#if HAVE_FP8_CVT
  f32x2 p0 = __builtin_amdgcn_cvt_pk_f32_fp8((int)u.x, false);
  f32x2 p1 = __builtin_amdgcn_cvt_pk_f32_fp8((int)u.x, true);
  f32x2 p2 = __builtin_amdgcn_cvt_pk_f32_fp8((int)u.y, false);
  f32x2 p3 = __builtin_amdgcn_cvt_pk_f32_fp8((int)u.y, true);
  o[0] = p0[0]; o[1] = p0[1]; o[2] = p1[0]; o[3] = p1[1];
  o[4] = p2[0]; o[5] = p2[1]; o[6] = p3[0]; o[7] = p3[1];
#else
#pragma unroll
  for (int e = 0; e < 4; ++e) o[e] = e4m3_f((u.x >> (8 * e)) & 0xffu);
#pragma unroll
  for (int e = 0; e < 4; ++e) o[4 + e] = e4m3_f((u.y >> (8 * e)) & 0xffu);
#endif
}
__device__ __forceinline__ void dec8hi(uint4 u, float* o) {
#if HAVE_FP8_CVT
  f32x2 p0 = __builtin_amdgcn_cvt_pk_f32_fp8((int)u.z, false);
  f32x2 p1 = __builtin_amdgcn_cvt_pk_f32_fp8((int)u.z, true);
  f32x2 p2 = __builtin_amdgcn_cvt_pk_f32_fp8((int)u.w, false);
  f32x2 p3 = __builtin_amdgcn_cvt_pk_f32_fp8((int)u.w, true);
  o[0] = p0[0]; o[1] = p0[1]; o[2] = p1[0]; o[3] = p1[1];
  o[4] = p2[0]; o[5] = p2[1]; o[6] = p3[0]; o[7] = p3[1];
#else
#pragma unroll
  for (int e = 0; e < 4; ++e) o[e] = e4m3_f((u.z >> (8 * e)) & 0xffu);
#pragma unroll
  for (int e = 0; e < 4; ++e) o[4 + e] = e4m3_f((u.w >> (8 * e)) & 0xffu);
#endif
}

// ---- adj int32 [N][N] -> bitmask u64 [N][N/64] (4096 blocks, streaming) ----
__global__ __launch_bounds__(256) void k_bitmask(const int* __restrict__ adj,
                                                 u64* __restrict__ bm) {
  int i = blockIdx.x;
  int lane = threadIdx.x & 63;
  int wv = threadIdx.x >> 6;
  const int* row = adj + (size_t)i * NN;
  for (int wq = wv; wq < NN / 64; wq += 4) {
    u64 b = __ballot(row[wq * 64 + lane] > 0);
    if (lane == 0) bm[(size_t)i * (NN / 64) + wq] = b;
  }
}

// ---- fused tables + fragment-major mask (runs after k_bitmask) ----
__global__ __launch_bounds__(256) void k_prep(
    const float* __restrict__ emb, const float* __restrict__ W1,
    const float* __restrict__ W2, const float* __restrict__ linW,
    const u64* __restrict__ bm, u16* __restrict__ emb16,
    u16* __restrict__ WT1, u16* __restrict__ WT2, u16* __restrict__ linWT,
    unsigned int* __restrict__ bmF) {
  int idx = blockIdx.x * 256 + threadIdx.x;
  if (idx < 1048576) { emb16[idx] = f2us(emb[idx]); return; }
  idx -= 1048576;
  if (idx < 98304) {
    int h = idx / 32768, r = idx & 32767, f = r >> 8, k = r & 255;
    WT1[idx] = f2us(W1[h * 32768 + k * 128 + f]);
    return;
  }
  idx -= 98304;
  if (idx < 147456) {
    int h = idx / 49152, r = idx % 49152, f = r / 384, k = r % 384;
    WT2[idx] = f2us(W2[h * 49152 + k * 128 + f]);
    return;
  }
  idx -= 147456;
  if (idx < 49152) {
    int f = idx / 384, k = idx % 384;
    linWT[idx] = f2us(linW[k * 128 + f]);
    return;
  }
  idx -= 49152;
  if (idx < 524288) {  // maskf: bmF[ib(64)][jc(128)][lane(64)]
    int l = idx & 63, jc = (idx >> 6) & 127, ib = idx >> 13;
    int li = l & 15, lg = l >> 4;
    const unsigned char* b8 = (const unsigned char*)bm;
    unsigned int v = 0;
#pragma unroll
    for (int m = 0; m < 4; ++m)
      v |= (unsigned int)b8[(size_t)(ib * 64 + m * 16 + li) * 512 + jc * 4 + lg]
           << (8 * m);
    bmF[idx] = v;
  }
}

// ---- Wh = x @ W via MFMA, v2: x-row loaded upfront, 3-deep register B
//      prefetch, fully unrolled (all static indices); 1 wave / 16 rows ----
template <int K>
__global__ __launch_bounds__(64, 2) void k_wh(const u16* __restrict__ xb,
                                              const u16* __restrict__ WT,
                                              const float* __restrict__ av,
                                              u16* __restrict__ WhTF,
                                              float* __restrict__ E1,
                                              float* __restrict__ F1,
                                              u16* __restrict__ E2h,
                                              u16* __restrict__ F2h) {
  constexpr int NS = K / 32;
  int h = blockIdx.y, l = threadIdx.x, li = l & 15, lg = l >> 4;
  int iw = blockIdx.x * 16;
  const u16* Wb = WT + (size_t)h * 128 * K;
  const u16* xr = xb + (size_t)(iw + li) * K;

  f32x4 acc[8];
#pragma unroll
  for (int nt = 0; nt < 8; ++nt) acc[nt] = (f32x4){0.f, 0.f, 0.f, 0.f};

  uint4 xa[NS];
#pragma unroll
  for (int s = 0; s < NS; ++s)
    xa[s] = *(const uint4*)(xr + s * 32 + lg * 8);

  uint4 bbuf[3][8];
#define LDB(S)                                                               \
  do {                                                                       \
    _Pragma("unroll") for (int nt = 0; nt < 8; ++nt)                         \
        bbuf[(S) % 3][nt] = *(const uint4*)(Wb + (size_t)(nt * 16 + li) * K +\
                                            (S) * 32 + lg * 8);              \
  } while (0)

#pragma unroll
  for (int pf = 0; pf < 3; ++pf) {
    if (pf < NS) LDB(pf);
  }
#pragma unroll
  for (int s = 0; s < NS; ++s) {
    U8 af;
    af.u = xa[s];
#pragma unroll
    for (int nt = 0; nt < 8; ++nt) {
      U8 bb;
      bb.u = bbuf[s % 3][nt];
      acc[nt] = __builtin_amdgcn_mfma_f32_16x16x32_bf16(af.b, bb.b, acc[nt], 0, 0, 0);
    }
    if (s + 3 < NS) LDB(s + 3);
  }
#undef LDB

  float p1[4] = {0.f, 0.f, 0.f, 0.f}, p2[4] = {0.f, 0.f, 0.f, 0.f};
#pragma unroll
  for (int nt = 0; nt < 8; ++nt) {
    float a1 = av[h * 256 + nt * 16 + li];
    float a2 = av[h * 256 + 128 + nt * 16 + li];
#pragma unroll
    for (int r = 0; r < 4; ++r) {
      p1[r] = fmaf(acc[nt][r], a1, p1[r]);
      p2[r] = fmaf(acc[nt][r], a2, p2[r]);
    }
  }
#pragma unroll
  for (int r = 0; r < 4; ++r) {
#pragma unroll
    for (int o = 1; o < 16; o <<= 1) {
      p1[r] += __shfl_xor(p1[r], o);
      p2[r] += __shfl_xor(p2[r], o);
    }
  }
  if (li == 0) {
#pragma unroll
    for (int r = 0; r < 4; ++r) {
      int idx = h * NN + iw + lg * 4 + r;
      float s1L = p1[r] * LOG2E, s2L = p2[r] * LOG2E;
      E1[idx] = exp2fast(s1L);
      F1[idx] = exp2fast(0.2f * s1L);
      E2h[idx] = f2h16(exp2fast(s2L));
      F2h[idx] = f2h16(exp2fast(0.2f * s2L));
    }
  }
  // fragment-major f16 write
  u16* Wo = WhTF + (size_t)h * 524288;
  int jc = iw >> 5, jin = (iw & 31) + lg * 4;
#pragma unroll
  for (int nt = 0; nt < 8; ++nt) {
    uint2 pw;
    pw.x = pkh2(acc[nt][0], acc[nt][1]);
    pw.y = pkh2(acc[nt][2], acc[nt][3]);
    *(uint2*)(Wo + (size_t)nt * 65536 + (size_t)jc * 512 + li * 32 + jin) = pw;
  }
}

// ---- attention accumulate v8 (f16): 4-wave/256-thr blocks, wave = M=32 x
//      N=128 x K=512 (kq=8); grid 32x8x3 = 768 = 3 blocks/CU; counted
//      vmcnt(2) pipeline; packed-f16 p-compute; f16 MFMA; T5 setprio ----
#define WAITC(N)                                                  \
  do {                                                            \
    asm volatile("s_waitcnt vmcnt(" #N ")" ::: "memory");         \
    __builtin_amdgcn_sched_barrier(0);                            \
    __builtin_amdgcn_s_barrier();                                 \
    __builtin_amdgcn_sched_barrier(0);                            \
  } while (0)
#define ROT3(X) X = (X == 2) ? 0 : X + 1

__global__ __launch_bounds__(256, 3) void k_acc(
    const unsigned int* __restrict__ bmF, const u16* __restrict__ WhTF,
    const float* __restrict__ E1, const float* __restrict__ F1,
    const u16* __restrict__ E2h, const u16* __restrict__ F2h,
    u16* __restrict__ Pp, float* __restrict__ dnP) {
  __shared__ __align__(16) u16 Bl[3][4096];  // 3 x 8KB
  int h = blockIdx.y, t = threadIdx.x, w = t >> 6, l = t & 63;
  int li = l & 15, lg = l >> 4;
  int rt = blockIdx.x >> 3, kq = blockIdx.x & 7;  // 32 rt x 8 kq
  int iw0 = rt * 128 + w * 32;
  int k0 = kq * 512;
  int perm = (l & 15) * 4 + (l >> 4);
  const u16* gsrcA = WhTF + (size_t)h * 524288 + (size_t)w * 65536 +
                     (size_t)(k0 >> 5) * 512 + perm * 8;
  const u16* gsrcB = gsrcA + (size_t)4 * 65536;
  const u16* E2p = E2h + h * NN;
  const u16* F2p = F2h + h * NN;
  f16x2 e1h[2], f1h[2];
#pragma unroll
  for (int mg = 0; mg < 2; ++mg) {
    f16_t e1 = (f16_t)E1[h * NN + iw0 + mg * 16 + li];
    f16_t f1 = (f16_t)F1[h * NN + iw0 + mg * 16 + li];
    e1h[mg][0] = e1; e1h[mg][1] = e1;
    f1h[mg][0] = f1; f1h[mg][1] = f1;
  }
  int mq0 = (iw0 >> 4) & 3;
  const unsigned int* mrow =
      bmF + ((size_t)(iw0 >> 6) * 128 + (k0 >> 5)) * 64 + l;

  f32x4 acc[2][8];
  f32x4 accD[2];
#pragma unroll
  for (int mg = 0; mg < 2; ++mg) {
    accD[mg] = (f32x4){0.f, 0.f, 0.f, 0.f};
#pragma unroll
    for (int nt = 0; nt < 8; ++nt) acc[mg][nt] = (f32x4){0.f, 0.f, 0.f, 0.f};
  }
  UH ones;
  ones.u = make_uint4(0x3C003C00u, 0x3C003C00u, 0x3C003C00u, 0x3C003C00u);

#define STG2(B, S)                                        \
  do {                                                    \
    gl_lds16(gsrcA + (size_t)(S) * 512, &Bl[B][w * 512]); \
    gl_lds16(gsrcB + (size_t)(S) * 512, &Bl[B][(w + 4) * 512]); \
  } while (0)
#define LDSC(SUF, S)                                      \
  do {                                                    \
    int j0_ = k0 + (S) * 32;                              \
    mw##SUF = mrow[(S) * 64];                             \
    Eu##SUF = *(const uint4*)(E2p + j0_ + lg * 8);        \
    Fu##SUF = *(const uint4*)(F2p + j0_ + lg * 8);        \
  } while (0)
#define BODY(SUF)                                                            \
  do {                                                                       \
    unsigned int ew_[4] = {Eu##SUF.x, Eu##SUF.y, Eu##SUF.z, Eu##SUF.w};      \
    unsigned int fw_[4] = {Fu##SUF.x, Fu##SUF.y, Fu##SUF.z, Fu##SUF.w};      \
    UH A_[2];                                                                \
    _Pragma("unroll") for (int mg = 0; mg < 2; ++mg) {                       \
      unsigned int mb_ = (mw##SUF >> (8 * (mq0 + mg))) & 0xffu;              \
      unsigned int aw_[4];                                                   \
      _Pragma("unroll") for (int q = 0; q < 4; ++q) {                        \
        UH2 eh_, fh_, ph_;                                                   \
        eh_.u = ew_[q];                                                      \
        fh_.u = fw_[q];                                                      \
        ph_.h = h2max(e1h[mg] * eh_.h, f1h[mg] * fh_.h);                     \
        unsigned int sel_ = (((mb_ >> (2 * q)) & 1u) ? 0xFFFFu : 0u) |       \
                            (((mb_ >> (2 * q + 1)) & 1u) ? 0xFFFF0000u : 0u);\
        aw_[q] = ph_.u & sel_;                                               \
      }                                                                      \
      A_[mg].u = make_uint4(aw_[0], aw_[1], aw_[2], aw_[3]);                 \
    }                                                                        \
    const u16* bl_ = &Bl[bcur][0] + l * 8;                                   \
    __builtin_amdgcn_s_setprio(1);                                           \
    _Pragma("unroll") for (int nt = 0; nt < 8; ++nt) {                       \
      UH B_;                                                                 \
      B_.u = *(const uint4*)(bl_ + nt * 512);                                \
      acc[0][nt] = __builtin_amdgcn_mfma_f32_16x16x32_f16(A_[0].h, B_.h,     \
                                                  acc[0][nt], 0, 0, 0);      \
      acc[1][nt] = __builtin_amdgcn_mfma_f32_16x16x32_f16(A_[1].h, B_.h,     \
                                                  acc[1][nt], 0, 0, 0);      \
    }                                                                        \
    accD[0] = __builtin_amdgcn_mfma_f32_16x16x32_f16(A_[0].h, ones.h,        \
                                                     accD[0], 0, 0, 0);      \
    accD[1] = __builtin_amdgcn_mfma_f32_16x16x32_f16(A_[1].h, ones.h,        \
                                                     accD[1], 0, 0, 0);      \
    __builtin_amdgcn_s_setprio(0);                                           \
    ROT3(bcur);                                                              \
  } while (0)

  unsigned int mwA, mwB;
  uint4 EuA, FuA, EuB, FuB;
  int bcur = 0, bstg = 2;
  LDSC(A, 0);
  STG2(0, 0);
  STG2(1, 1);
#pragma unroll 1
  for (int s = 0; s < 16; s += 2) {
    WAITC(2);
    LDSC(B, s + 1);
    if (s + 2 < 16) { STG2(bstg, s + 2); ROT3(bstg); }
    BODY(A);
    if (s + 1 == 15) { WAITC(0); } else { WAITC(2); }
    if (s + 2 < 16) LDSC(A, s + 2);
    if (s + 3 < 16) { STG2(bstg, s + 3); ROT3(bstg); }
    BODY(B);
  }
#undef STG2
#undef LDSC
#undef BODY

#pragma unroll
  for (int mg = 0; mg < 2; ++mg) {
    size_t rbase = (size_t)(kq * 3 + h) * NN + iw0 + mg * 16;
#pragma unroll
    for (int nt = 0; nt < 8; ++nt)
#pragma unroll
      for (int r = 0; r < 4; ++r)
        Pp[(rbase + lg * 4 + r) * 128 + nt * 16 + li] = f2us(acc[mg][nt][r]);
    if (li == 0) {
#pragma unroll
      for (int r = 0; r < 4; ++r)
        dnP[rbase + lg * 4 + r] = accD[mg][r];
    }
  }
}

// ---- finalize: sum 8 bf16 K-chunk partials, /dn, ELU, mix (bf16 at1);
//      mode1 -> fp8 pair-table att8 in 2-step-packed layout ----
__global__ __launch_bounds__(256) void k_fin(
    const u16* __restrict__ Pp, const float* __restrict__ dnP,
    const u16* __restrict__ at1b_in, const float* __restrict__ amix,
    const float* __restrict__ bmix, u16* __restrict__ at1b_out,
    unsigned char* __restrict__ att8_out, int mode) {
  int gid = blockIdx.x * 256 + threadIdx.x;
  int c4 = gid & 31, row = (gid >> 5) & 4095, h = gid >> 17;
  size_t off = ((size_t)h * NN + row) * 128 + c4 * 4;
  const size_t ks = (size_t)3 * NN * 128;
  float s[4] = {0.f, 0.f, 0.f, 0.f};
  float dsum = 0.f;
#pragma unroll
  for (int q = 0; q < 8; ++q) {
    uint2 v = *(const uint2*)(Pp + q * ks + off);
    s[0] += us2f((u16)(v.x & 0xffffu));
    s[1] += us2f((u16)(v.x >> 16));
    s[2] += us2f((u16)(v.y & 0xffffu));
    s[3] += us2f((u16)(v.y >> 16));
    dsum += dnP[(size_t)(q * 3 + h) * NN + row];
  }
  float inv = 1.f / fmaxf(dsum, 1e-30f);
#pragma unroll
  for (int q = 0; q < 4; ++q) {
    s[q] *= inv;
    s[q] = s[q] > 0.f ? s[q] : (exp2fast(s[q] * LOG2E) - 1.f);
  }
  size_t oi = (size_t)row * 384 + h * 128 + c4 * 4;
  if (mode == 0) {
    uint2 pb;
    pb.x = pk2(s[0], s[1]);
    pb.y = pk2(s[2], s[3]);
    *(uint2*)(at1b_out + oi) = pb;
  } else {
    float Am = amix[0], Bm = bmix[0];
    float wa = Am / (Am + Bm), wb = Bm / (Am + Bm);
    uint2 a1 = *(const uint2*)(at1b_in + oi);
    float m0 = wa * us2f((u16)(a1.x & 0xffffu)) + wb * s[0];
    float m1 = wa * us2f((u16)(a1.x >> 16)) + wb * s[1];
    float m2 = wa * us2f((u16)(a1.y & 0xffffu)) + wb * s[2];
    float m3 = wa * us2f((u16)(a1.y >> 16)) + wb * s[3];
#if HAVE_FP8_CVT
    int v8 = __builtin_amdgcn_cvt_pk_fp8_f32(m0, m1, 0, false);
    v8 = __builtin_amdgcn_cvt_pk_fp8_f32(m2, m3, v8, true);
#else
    unsigned int v8 = f_e4m3(m0) | (f_e4m3(m1) << 8) | (f_e4m3(m2) << 16) |
                      (f_e4m3(m3) << 24);
#endif
    int gc = h * 128 + c4 * 4;  // global col 0..383
    int st = gc >> 5, lg2 = (gc >> 3) & 3, e0 = gc & 7;
    int kp = (st >> 1) * 64 + lg2 * 16 + (st & 1) * 8 + e0;
    *(unsigned int*)(att8_out + (size_t)row * 384 + kp) = (unsigned int)v8;
  }
}

// ---- pair scoring v4: fp8 gathers, depth-3 prefetch, fast-gelu epilogue ----
__global__ __launch_bounds__(1024) void k_pairs(
    const int* __restrict__ aidx, const int* __restrict__ bidx,
    const unsigned char* __restrict__ att8, const u16* __restrict__ linWT,
    const float* __restrict__ linB, const float* __restrict__ outW,
    const float* __restrict__ outB, const float* __restrict__ embB,
    float* __restrict__ out) {
  __shared__ __align__(16) u16 Wlds[128][392];  // ~100KB
  int t = threadIdx.x, w = t >> 6, l = t & 63;
  int li = l & 15, lg = l >> 4;
  {
    int r = t >> 3, seg = (t & 7) * 48;
    const u16* src = linWT + (size_t)r * 384 + seg;
    u16* dst = &Wlds[r][seg];
#pragma unroll
    for (int q = 0; q < 6; ++q)
      *(uint4*)(dst + q * 8) = *(const uint4*)(src + q * 8);
  }
  __syncthreads();

  int p0 = blockIdx.x * 512 + w * 32;
  int ia0 = aidx[p0 + li], ib0 = bidx[p0 + li];
  int ia1 = aidx[p0 + 16 + li], ib1 = bidx[p0 + 16 + li];
  const unsigned char* ra0 = att8 + (size_t)ia0 * 384;
  const unsigned char* rb0 = att8 + (size_t)ib0 * 384;
  const unsigned char* ra1 = att8 + (size_t)ia1 * 384;
  const unsigned char* rb1 = att8 + (size_t)ib1 * 384;
  int boff = lg * 16;

  f32x4 acc[2][8];
#pragma unroll
  for (int g = 0; g < 2; ++g)
#pragma unroll
    for (int nt = 0; nt < 8; ++nt) acc[g][nt] = (f32x4){0.f, 0.f, 0.f, 0.f};

#define LDG8(BUF, S2)                               \
  do {                                              \
    int o_ = (S2) * 64 + boff;                      \
    BUF[0] = *(const uint4*)(ra0 + o_);             \
    BUF[1] = *(const uint4*)(rb0 + o_);             \
    BUF[2] = *(const uint4*)(ra1 + o_);             \
    BUF[3] = *(const uint4*)(rb1 + o_);             \
  } while (0)
#define WORK8(BUF, S2)                                                       \
  do {                                                                       \
    _Pragma("unroll") for (int hf = 0; hf < 2; ++hf) {                       \
      float a0_[8], b0_[8], a1_[8], b1_[8];                                  \
      if (hf == 0) {                                                         \
        dec8lo(BUF[0], a0_); dec8lo(BUF[1], b0_);                            \
        dec8lo(BUF[2], a1_); dec8lo(BUF[3], b1_);                            \
      } else {                                                               \
        dec8hi(BUF[0], a0_); dec8hi(BUF[1], b0_);                            \
        dec8hi(BUF[2], a1_); dec8hi(BUF[3], b1_);                            \
      }                                                                      \
      U8 af0_, af1_;                                                         \
      _Pragma("unroll") for (int e = 0; e < 8; ++e) {                        \
        af0_.b[e] = (bf16_t)(a0_[e] * b0_[e]);                               \
        af1_.b[e] = (bf16_t)(a1_[e] * b1_[e]);                               \
      }                                                                      \
      int j0_ = ((S2) * 2 + hf) * 32 + lg * 8;                               \
      _Pragma("unroll") for (int nt = 0; nt < 8; ++nt) {                     \
        U8 bb_;                                                              \
        bb_.u = *(const uint4*)&Wlds[nt * 16 + li][j0_];                     \
        acc[0][nt] = __builtin_amdgcn_mfma_f32_16x16x32_bf16(af0_.b, bb_.b,  \
                                                    acc[0][nt], 0, 0, 0);    \
        acc[1][nt] = __builtin_amdgcn_mfma_f32_16x16x32_bf16(af1_.b, bb_.b,  \
                                                    acc[1][nt], 0, 0, 0);    \
      }                                                                      \
    }                                                                        \
  } while (0)

  uint4 bX[4], bY[4], bZ[4];
  LDG8(bX, 0);
  LDG8(bY, 1);
  LDG8(bZ, 2);
  WORK8(bX, 0);
  LDG8(bX, 3);
  WORK8(bY, 1);
  LDG8(bY, 4);
  WORK8(bZ, 2);
  LDG8(bZ, 5);
  WORK8(bX, 3);
  WORK8(bY, 4);
  WORK8(bZ, 5);
#undef LDG8
#undef WORK8

#pragma unroll
  for (int g = 0; g < 2; ++g) {
    float z[4] = {0.f, 0.f, 0.f, 0.f};
#pragma unroll
    for (int nt = 0; nt < 8; ++nt) {
      int f = nt * 16 + li;
      float lb = linB[f], ow = outW[f];
#pragma unroll
      for (int r = 0; r < 4; ++r) {
        float y = geluf(acc[g][nt][r] + lb);
        z[r] = fmaf(y, ow, z[r]);
      }
    }
#pragma unroll
    for (int r = 0; r < 4; ++r) {
      z[r] += __shfl_xor(z[r], 1);
      z[r] += __shfl_xor(z[r], 2);
      z[r] += __shfl_xor(z[r], 4);
      z[r] += __shfl_xor(z[r], 8);
    }
    if (li == 0) {
#pragma unroll
      for (int r = 0; r < 4; ++r) {
        int pi = p0 + g * 16 + lg * 4 + r;
        float badd = geluf(embB[aidx[pi]] + embB[bidx[pi]]);
        float zz = z[r] + badd * outW[128] + outB[0];
        out[pi] = 1.f / (1.f + __expf(-zz));
      }
    }
  }
}

extern "C" void kernel_launch(void* const* d_in, const int* in_sizes, int n_in,
                              void* d_out, int out_size, void* d_ws, size_t ws_size,
                              hipStream_t stream) {
  (void)in_sizes; (void)n_in; (void)out_size; (void)ws_size;
  const int* aidx = (const int*)d_in[0];
  const int* bidx = (const int*)d_in[1];
  const int* adj = (const int*)d_in[2];
  const float* emb = (const float*)d_in[3];
  const float* embB = (const float*)d_in[4];
  const float* W1 = (const float*)d_in[5];
  const float* av1 = (const float*)d_in[6];
  const float* W2 = (const float*)d_in[7];
  const float* av2 = (const float*)d_in[8];
  const float* amix = (const float*)d_in[9];
  const float* bmix = (const float*)d_in[10];
  const float* linW = (const float*)d_in[11];
  const float* linB = (const float*)d_in[12];
  const float* outW = (const float*)d_in[13];
  const float* outB = (const float*)d_in[14];

  char* ws = (char*)d_ws;
  u64* bm = (u64*)(ws + 0);                           // 2MB
  u16* WhTF = (u16*)(ws + (2u << 20));                // 3MB fragment-major f16
  float* E1 = (float*)(ws + (5u << 20));              // 48KB each
  float* F1 = (float*)(ws + (5u << 20) + (64u << 10));
  u16* E2h = (u16*)(ws + (5u << 20) + (128u << 10));  // 24KB f16
  u16* F2h = (u16*)(ws + (5u << 20) + (192u << 10));  // 24KB f16
  u16* linWT = (u16*)(ws + (5u << 20) + (256u << 10));  // 96KB
  u16* WT1 = (u16*)(ws + (5u << 20) + (384u << 10));    // 192KB
  u16* WT2 = (u16*)(ws + (5u << 20) + (640u << 10));    // 288KB
  u16* sh12 = (u16*)(ws + (12u << 20));               // 3MB: emb16 -> at1b
  u16* emb16 = sh12;
  u16* at1b = sh12;
  unsigned int* bmF = (unsigned int*)(ws + (15u << 20));  // 2MB
  u16* Pp = (u16*)(ws + (17u << 20));                 // 24MiB bf16 partials
  float* dnP = (float*)(ws + (41u << 20));            // 384KB dn partials
  unsigned char* att8 = (unsigned char*)(ws + (42u << 20));  // 1.5MB fp8 table

  k_bitmask<<<NN, 256, 0, stream>>>(adj, bm);
  k_prep<<<7296, 256, 0, stream>>>(emb, W1, W2, linW, bm, emb16, WT1, WT2,
                                   linWT, bmF);
  k_wh<256><<<dim3(256, NH), 64, 0, stream>>>(emb16, WT1, av1, WhTF, E1, F1, E2h, F2h);
  k_acc<<<dim3(256, NH), 256, 0, stream>>>(bmF, WhTF, E1, F1, E2h, F2h, Pp, dnP);
  k_fin<<<1536, 256, 0, stream>>>(Pp, dnP, at1b, amix, bmix, at1b, att8, 0);
  k_wh<384><<<dim3(256, NH), 64, 0, stream>>>(at1b, WT2, av2, WhTF, E1, F1, E2h, F2h);
  k_acc<<<dim3(256, NH), 256, 0, stream>>>(bmF, WhTF, E1, F1, E2h, F2h, Pp, dnP);
  k_fin<<<1536, 256, 0, stream>>>(Pp, dnP, at1b, amix, bmix, at1b, att8, 1);
  k_pairs<<<NPAIR / 512, 1024, 0, stream>>>(aidx, bidx, att8, linWT, linB, outW,
                                            outB, embB, (float*)d_out);
}